// Round 1
// baseline (426.013 us; speedup 1.0000x reference)
//
#include <hip/hip_runtime.h>
#include <math.h>

#define C_DIM 96
#define CR 24
#define H_DIM 128
#define W_DIM 128
#define B_DIM 32

// ---------------- Kernel 1: adaptive avg pool (per-plane mean) ----------------
__global__ void pool_kernel(const float* __restrict__ x, float* __restrict__ pooled) {
    int plane = blockIdx.x;                       // b*96 + c, 3072 planes
    const float4* xp = (const float4*)(x + (size_t)plane * (H_DIM * W_DIM));
    float s = 0.f;
    // 16384 floats = 4096 float4 per plane; 256 threads -> 16 each
    for (int i = threadIdx.x; i < 4096; i += 256) {
        float4 v = xp[i];
        s += v.x + v.y + v.z + v.w;
    }
    // wave64 shuffle reduce
    for (int off = 32; off; off >>= 1) s += __shfl_down(s, off, 64);
    __shared__ float ls[4];
    int lane = threadIdx.x & 63, wv = threadIdx.x >> 6;
    if (lane == 0) ls[wv] = s;
    __syncthreads();
    if (threadIdx.x == 0) {
        float t = ls[0] + ls[1] + ls[2] + ls[3];
        pooled[plane] = t * (1.f / (H_DIM * W_DIM));
    }
}

// ---------------- Kernel 2: dynamic weight MLP (tiny) ----------------
__global__ void wdyn_kernel(const float* __restrict__ pooled,
                            const float* __restrict__ w1,
                            const float* __restrict__ gamma,
                            const float* __restrict__ beta,
                            const float* __restrict__ rmean,
                            const float* __restrict__ rvar,
                            const float* __restrict__ w2,
                            const float* __restrict__ b2,
                            float* __restrict__ wdyn) {
    int b = blockIdx.x;                 // 32 blocks
    int tid = threadIdx.x;              // 256 threads
    __shared__ float pl[C_DIM];
    __shared__ float h1[CR];
    if (tid < C_DIM) pl[tid] = pooled[b * C_DIM + tid];
    __syncthreads();
    if (tid < CR) {
        float s = 0.f;
        const float* wr = w1 + tid * C_DIM;
        for (int c = 0; c < C_DIM; c++) s += pl[c] * wr[c];
        s = (s - rmean[tid]) * rsqrtf(rvar[tid] + 1e-5f) * gamma[tid] + beta[tid];
        h1[tid] = 1.f / (1.f + expf(-s));
    }
    __syncthreads();
    for (int o = tid; o < C_DIM * 9; o += 256) {
        float s = b2[o];
        const float* wr = w2 + o * CR;
        #pragma unroll
        for (int j = 0; j < CR; j++) s += h1[j] * wr[j];
        wdyn[b * (C_DIM * 9) + o] = s;
    }
}

// ---------------- Kernel 3: per-sample depthwise 3x3, vertical sliding window ----------------
__global__ void __launch_bounds__(256) dwconv_kernel(const float* __restrict__ x,
                                                     const float* __restrict__ wdyn,
                                                     const float* __restrict__ bias,
                                                     float* __restrict__ out) {
    // one thread per (plane, col); 32*96 planes * 128 cols = 393216 threads
    int gid = blockIdx.x * 256 + threadIdx.x;
    int col = gid & (W_DIM - 1);
    int plane = gid >> 7;                        // b*96 + c
    int c = plane % C_DIM;
    const float* xp = x + (size_t)plane * (H_DIM * W_DIM);
    float* op = out + (size_t)plane * (H_DIM * W_DIM);
    const float* wp = wdyn + (size_t)plane * 9;
    float w00 = wp[0], w01 = wp[1], w02 = wp[2];
    float w10 = wp[3], w11 = wp[4], w12 = wp[5];
    float w20 = wp[6], w21 = wp[7], w22 = wp[8];
    float bb = bias[c];
    const bool hasL = (col > 0), hasR = (col < W_DIM - 1);

    // taps: rows r-1 (p), r (cur), r+1 (n)
    float p0 = 0.f, p1 = 0.f, p2 = 0.f;
    float c0, c1, c2, n0, n1, n2;
    c0 = hasL ? xp[col - 1] : 0.f;
    c1 = xp[col];
    c2 = hasR ? xp[col + 1] : 0.f;

    #pragma unroll 4
    for (int r = 0; r < H_DIM; r++) {
        if (r < H_DIM - 1) {
            const float* row = xp + (r + 1) * W_DIM;
            n0 = hasL ? row[col - 1] : 0.f;
            n1 = row[col];
            n2 = hasR ? row[col + 1] : 0.f;
        } else {
            n0 = n1 = n2 = 0.f;
        }
        float s = w00 * p0 + w01 * p1 + w02 * p2
                + w10 * c0 + w11 * c1 + w12 * c2
                + w20 * n0 + w21 * n1 + w22 * n2 + bb;
        op[r * W_DIM + col] = s;
        p0 = c0; p1 = c1; p2 = c2;
        c0 = n0; c1 = n1; c2 = n2;
    }
}

extern "C" void kernel_launch(void* const* d_in, const int* in_sizes, int n_in,
                              void* d_out, int out_size, void* d_ws, size_t ws_size,
                              hipStream_t stream) {
    const float* x     = (const float*)d_in[0];
    const float* w1    = (const float*)d_in[1];
    const float* gamma = (const float*)d_in[2];
    const float* beta  = (const float*)d_in[3];
    const float* rmean = (const float*)d_in[4];
    const float* rvar  = (const float*)d_in[5];
    const float* w2    = (const float*)d_in[6];
    const float* b2    = (const float*)d_in[7];
    const float* bias  = (const float*)d_in[8];
    float* out = (float*)d_out;

    float* pooled = (float*)d_ws;                           // 3072 floats
    float* wdyn   = pooled + B_DIM * C_DIM;                 // 27648 floats

    // 1) pooling: one block per (b,c) plane
    pool_kernel<<<B_DIM * C_DIM, 256, 0, stream>>>(x, pooled);
    // 2) dynamic weights: one block per batch
    wdyn_kernel<<<B_DIM, 256, 0, stream>>>(pooled, w1, gamma, beta, rmean, rvar, w2, b2, wdyn);
    // 3) depthwise conv
    int total_threads = B_DIM * C_DIM * W_DIM;              // 393216
    dwconv_kernel<<<total_threads / 256, 256, 0, stream>>>(x, wdyn, bias, out);
}

// Round 2
// 396.076 us; speedup vs baseline: 1.0756x; 1.0756x over previous
//
#include <hip/hip_runtime.h>
#include <math.h>

#define C_DIM 96
#define CR 24
#define H_DIM 128
#define W_DIM 128
#define B_DIM 32
#define CHUNKS 4
#define ROWS_PER_CHUNK (H_DIM / CHUNKS)

// ---------------- Kernel 1: adaptive avg pool (per-plane mean) ----------------
__global__ void pool_kernel(const float* __restrict__ x, float* __restrict__ pooled) {
    int plane = blockIdx.x;                       // b*96 + c, 3072 planes
    const float4* xp = (const float4*)(x + (size_t)plane * (H_DIM * W_DIM));
    float s = 0.f;
    // 16384 floats = 4096 float4 per plane; 256 threads -> 16 each
    for (int i = threadIdx.x; i < 4096; i += 256) {
        float4 v = xp[i];
        s += v.x + v.y + v.z + v.w;
    }
    // wave64 shuffle reduce
    for (int off = 32; off; off >>= 1) s += __shfl_down(s, off, 64);
    __shared__ float ls[4];
    int lane = threadIdx.x & 63, wv = threadIdx.x >> 6;
    if (lane == 0) ls[wv] = s;
    __syncthreads();
    if (threadIdx.x == 0) {
        float t = ls[0] + ls[1] + ls[2] + ls[3];
        pooled[plane] = t * (1.f / (H_DIM * W_DIM));
    }
}

// ---------------- Kernel 2: dynamic weight MLP (tiny) ----------------
__global__ void wdyn_kernel(const float* __restrict__ pooled,
                            const float* __restrict__ w1,
                            const float* __restrict__ gamma,
                            const float* __restrict__ beta,
                            const float* __restrict__ rmean,
                            const float* __restrict__ rvar,
                            const float* __restrict__ w2,
                            const float* __restrict__ b2,
                            float* __restrict__ wdyn) {
    int b = blockIdx.x;                 // 32 blocks
    int tid = threadIdx.x;              // 256 threads
    __shared__ float pl[C_DIM];
    __shared__ float h1[CR];
    if (tid < C_DIM) pl[tid] = pooled[b * C_DIM + tid];
    __syncthreads();
    if (tid < CR) {
        float s = 0.f;
        const float* wr = w1 + tid * C_DIM;
        for (int c = 0; c < C_DIM; c++) s += pl[c] * wr[c];
        s = (s - rmean[tid]) * rsqrtf(rvar[tid] + 1e-5f) * gamma[tid] + beta[tid];
        h1[tid] = 1.f / (1.f + expf(-s));
    }
    __syncthreads();
    for (int o = tid; o < C_DIM * 9; o += 256) {
        float s = b2[o];
        const float* wr = w2 + o * CR;
        #pragma unroll
        for (int j = 0; j < CR; j++) s += h1[j] * wr[j];
        wdyn[b * (C_DIM * 9) + o] = s;
    }
}

// ---------------- Kernel 3: per-sample depthwise 3x3, float4 + lane-shuffle halo ----------------
// Thread map: T = blockIdx*256 + tid
//   g     = T & 31        -> col group, cols [4g, 4g+3]
//   chunk = (T>>5) & 3    -> rows [32*chunk, 32*chunk+31]
//   plane = T >> 7        -> b*96 + c
// Lanes 0..31 / 32..63 of a wave are different (chunk or plane) segments, but the
// shuffle exchange at the lane 31<->32 boundary is exactly the g==31 right edge /
// g==0 left edge, which is zeroed anyway.
__global__ void __launch_bounds__(256) dwconv_kernel(const float* __restrict__ x,
                                                     const float* __restrict__ wdyn,
                                                     const float* __restrict__ bias,
                                                     float* __restrict__ out) {
    int T = blockIdx.x * 256 + threadIdx.x;
    int g = T & 31;
    int chunk = (T >> 5) & 3;
    int plane = T >> 7;
    int c = plane % C_DIM;
    int col = g << 2;
    int r0 = chunk * ROWS_PER_CHUNK;

    const float* xp = x + (size_t)plane * (H_DIM * W_DIM);
    float* op = out + (size_t)plane * (H_DIM * W_DIM);
    const float* wp = wdyn + (size_t)plane * 9;
    float w00 = wp[0], w01 = wp[1], w02 = wp[2];
    float w10 = wp[3], w11 = wp[4], w12 = wp[5];
    float w20 = wp[6], w21 = wp[7], w22 = wp[8];
    float bb = bias[c];
    const bool leftEdge = (g == 0), rightEdge = (g == 31);

    float4 pv, cv, nv;
    float pl, pr, cl, cr_, nl, nr;

    // row r0-1
    {
        int r = r0 - 1;
        float4 v;
        if (r >= 0) v = *(const float4*)(xp + r * W_DIM + col);
        else { v.x = v.y = v.z = v.w = 0.f; }
        float l = __shfl_up(v.w, 1, 64);
        float rr = __shfl_down(v.x, 1, 64);
        pv = v; pl = leftEdge ? 0.f : l; pr = rightEdge ? 0.f : rr;
    }
    // row r0
    {
        float4 v = *(const float4*)(xp + r0 * W_DIM + col);
        float l = __shfl_up(v.w, 1, 64);
        float rr = __shfl_down(v.x, 1, 64);
        cv = v; cl = leftEdge ? 0.f : l; cr_ = rightEdge ? 0.f : rr;
    }

    #pragma unroll 4
    for (int i = 0; i < ROWS_PER_CHUNK; i++) {
        int r = r0 + i;
        // load row r+1 (valid unless r == 127)
        float4 v;
        if (r + 1 < H_DIM) v = *(const float4*)(xp + (r + 1) * W_DIM + col);
        else { v.x = v.y = v.z = v.w = 0.f; }
        float l = __shfl_up(v.w, 1, 64);
        float rr = __shfl_down(v.x, 1, 64);
        nv = v; nl = leftEdge ? 0.f : l; nr = rightEdge ? 0.f : rr;

        float4 o;
        o.x = w00 * pl   + w01 * pv.x + w02 * pv.y
            + w10 * cl   + w11 * cv.x + w12 * cv.y
            + w20 * nl   + w21 * nv.x + w22 * nv.y + bb;
        o.y = w00 * pv.x + w01 * pv.y + w02 * pv.z
            + w10 * cv.x + w11 * cv.y + w12 * cv.z
            + w20 * nv.x + w21 * nv.y + w22 * nv.z + bb;
        o.z = w00 * pv.y + w01 * pv.z + w02 * pv.w
            + w10 * cv.y + w11 * cv.z + w12 * cv.w
            + w20 * nv.y + w21 * nv.z + w22 * nv.w + bb;
        o.w = w00 * pv.z + w01 * pv.w + w02 * pr
            + w10 * cv.z + w11 * cv.w + w12 * cr_
            + w20 * nv.z + w21 * nv.w + w22 * nr + bb;
        *(float4*)(op + r * W_DIM + col) = o;

        pv = cv; pl = cl; pr = cr_;
        cv = nv; cl = nl; cr_ = nr;
    }
}

extern "C" void kernel_launch(void* const* d_in, const int* in_sizes, int n_in,
                              void* d_out, int out_size, void* d_ws, size_t ws_size,
                              hipStream_t stream) {
    const float* x     = (const float*)d_in[0];
    const float* w1    = (const float*)d_in[1];
    const float* gamma = (const float*)d_in[2];
    const float* beta  = (const float*)d_in[3];
    const float* rmean = (const float*)d_in[4];
    const float* rvar  = (const float*)d_in[5];
    const float* w2    = (const float*)d_in[6];
    const float* b2    = (const float*)d_in[7];
    const float* bias  = (const float*)d_in[8];
    float* out = (float*)d_out;

    float* pooled = (float*)d_ws;                           // 3072 floats
    float* wdyn   = pooled + B_DIM * C_DIM;                 // 27648 floats

    // 1) pooling: one block per (b,c) plane
    pool_kernel<<<B_DIM * C_DIM, 256, 0, stream>>>(x, pooled);
    // 2) dynamic weights: one block per batch
    wdyn_kernel<<<B_DIM, 256, 0, stream>>>(pooled, w1, gamma, beta, rmean, rvar, w2, b2, wdyn);
    // 3) depthwise conv: plane x chunk x colgroup threads
    int total_threads = B_DIM * C_DIM * CHUNKS * (W_DIM / 4);   // 393216
    dwconv_kernel<<<total_threads / 256, 256, 0, stream>>>(x, wdyn, bias, out);
}

// Round 4
// 387.565 us; speedup vs baseline: 1.0992x; 1.0220x over previous
//
#include <hip/hip_runtime.h>
#include <math.h>

#define C_DIM 96
#define CR 24
#define H_DIM 128
#define W_DIM 128
#define B_DIM 32
#define CHUNKS 4
#define ROWS_PER_CHUNK (H_DIM / CHUNKS)

typedef float nfloat4 __attribute__((ext_vector_type(4)));   // native vec for nontemporal builtin

// ---------------- Kernel 1: adaptive avg pool (per-plane mean) ----------------
__global__ void pool_kernel(const float* __restrict__ x, float* __restrict__ pooled) {
    int plane = blockIdx.x;                       // b*96 + c, 3072 planes
    const float4* xp = (const float4*)(x + (size_t)plane * (H_DIM * W_DIM));
    float s = 0.f;
    for (int i = threadIdx.x; i < 4096; i += 256) {
        float4 v = xp[i];
        s += v.x + v.y + v.z + v.w;
    }
    for (int off = 32; off; off >>= 1) s += __shfl_down(s, off, 64);
    __shared__ float ls[4];
    int lane = threadIdx.x & 63, wv = threadIdx.x >> 6;
    if (lane == 0) ls[wv] = s;
    __syncthreads();
    if (threadIdx.x == 0) {
        float t = ls[0] + ls[1] + ls[2] + ls[3];
        pooled[plane] = t * (1.f / (H_DIM * W_DIM));
    }
}

// ---------------- Kernel 2: fused dynamic-weight MLP + per-sample depthwise 3x3 ----------------
// Block covers 2 consecutive planes (same batch b: pairs (2p,2p+1) never straddle
// a multiple of 96). Prologue recomputes h1 + this block's 18 wdyn rows (~0.2 us).
// Main loop: float4 per thread, halo via lane shuffle, 4 row-chunks of 32.
//   tid map: g = tid&31 (col group), chunk = (tid>>5)&3, p = tid>>7 (0/1)
__global__ void __launch_bounds__(256) fused_dwconv_kernel(const float* __restrict__ x,
                                                           const float* __restrict__ pooled,
                                                           const float* __restrict__ w1,
                                                           const float* __restrict__ gamma,
                                                           const float* __restrict__ beta,
                                                           const float* __restrict__ rmean,
                                                           const float* __restrict__ rvar,
                                                           const float* __restrict__ w2,
                                                           const float* __restrict__ b2,
                                                           const float* __restrict__ bias,
                                                           float* __restrict__ out) {
    int tid = threadIdx.x;
    int plane0 = blockIdx.x * 2;            // even plane index
    int b = plane0 / C_DIM;
    int c0 = plane0 % C_DIM;                // channel of plane0; plane1 is c0+1

    __shared__ float pl[C_DIM];
    __shared__ float h1[CR];
    __shared__ float wsm[2][10];            // 9 taps + bias per plane

    if (tid < C_DIM) pl[tid] = pooled[b * C_DIM + tid];
    __syncthreads();
    if (tid < CR) {
        float s = 0.f;
        const float* wr = w1 + tid * C_DIM;
        #pragma unroll 8
        for (int c = 0; c < C_DIM; c++) s += pl[c] * wr[c];
        s = (s - rmean[tid]) * rsqrtf(rvar[tid] + 1e-5f) * gamma[tid] + beta[tid];
        h1[tid] = 1.f / (1.f + expf(-s));
    }
    __syncthreads();
    if (tid < 20) {
        if (tid < 18) {
            int p = tid / 9, k = tid % 9;
            int row = (c0 + p) * 9 + k;     // wdyn flat index within batch
            float s = b2[row];
            const float* wr = w2 + row * CR;
            #pragma unroll
            for (int j = 0; j < CR; j++) s += h1[j] * wr[j];
            wsm[p][k] = s;
        } else {
            wsm[tid - 18][9] = bias[c0 + (tid - 18)];
        }
    }
    __syncthreads();

    int g = tid & 31;
    int chunk = (tid >> 5) & 3;
    int p = tid >> 7;
    int plane = plane0 + p;
    int col = g << 2;
    int r0 = chunk * ROWS_PER_CHUNK;

    const float* xp = x + (size_t)plane * (H_DIM * W_DIM);
    float* op = out + (size_t)plane * (H_DIM * W_DIM);
    const float* wv = wsm[p];
    float w00 = wv[0], w01 = wv[1], w02 = wv[2];
    float w10 = wv[3], w11 = wv[4], w12 = wv[5];
    float w20 = wv[6], w21 = wv[7], w22 = wv[8];
    float bb = wv[9];
    const bool leftEdge = (g == 0), rightEdge = (g == 31);

    float4 pv, cv, nv;
    float plh, prh, clh, crh, nlh, nrh;

    {
        int r = r0 - 1;
        float4 v;
        if (r >= 0) v = *(const float4*)(xp + r * W_DIM + col);
        else { v.x = v.y = v.z = v.w = 0.f; }
        float l = __shfl_up(v.w, 1, 64);
        float rr = __shfl_down(v.x, 1, 64);
        pv = v; plh = leftEdge ? 0.f : l; prh = rightEdge ? 0.f : rr;
    }
    {
        float4 v = *(const float4*)(xp + r0 * W_DIM + col);
        float l = __shfl_up(v.w, 1, 64);
        float rr = __shfl_down(v.x, 1, 64);
        cv = v; clh = leftEdge ? 0.f : l; crh = rightEdge ? 0.f : rr;
    }

    #pragma unroll 4
    for (int i = 0; i < ROWS_PER_CHUNK; i++) {
        int r = r0 + i;
        float4 v;
        if (r + 1 < H_DIM) v = *(const float4*)(xp + (r + 1) * W_DIM + col);
        else { v.x = v.y = v.z = v.w = 0.f; }
        float l = __shfl_up(v.w, 1, 64);
        float rr = __shfl_down(v.x, 1, 64);
        nv = v; nlh = leftEdge ? 0.f : l; nrh = rightEdge ? 0.f : rr;

        nfloat4 o;
        o.x = w00 * plh  + w01 * pv.x + w02 * pv.y
            + w10 * clh  + w11 * cv.x + w12 * cv.y
            + w20 * nlh  + w21 * nv.x + w22 * nv.y + bb;
        o.y = w00 * pv.x + w01 * pv.y + w02 * pv.z
            + w10 * cv.x + w11 * cv.y + w12 * cv.z
            + w20 * nv.x + w21 * nv.y + w22 * nv.z + bb;
        o.z = w00 * pv.y + w01 * pv.z + w02 * pv.w
            + w10 * cv.y + w11 * cv.z + w12 * cv.w
            + w20 * nv.y + w21 * nv.z + w22 * nv.w + bb;
        o.w = w00 * pv.z + w01 * pv.w + w02 * prh
            + w10 * cv.z + w11 * cv.w + w12 * crh
            + w20 * nv.z + w21 * nv.w + w22 * nrh + bb;
        __builtin_nontemporal_store(o, (nfloat4*)(op + r * W_DIM + col));

        pv = cv; plh = clh; prh = crh;
        cv = nv; clh = nlh; crh = nrh;
    }
}

extern "C" void kernel_launch(void* const* d_in, const int* in_sizes, int n_in,
                              void* d_out, int out_size, void* d_ws, size_t ws_size,
                              hipStream_t stream) {
    const float* x     = (const float*)d_in[0];
    const float* w1    = (const float*)d_in[1];
    const float* gamma = (const float*)d_in[2];
    const float* beta  = (const float*)d_in[3];
    const float* rmean = (const float*)d_in[4];
    const float* rvar  = (const float*)d_in[5];
    const float* w2    = (const float*)d_in[6];
    const float* b2    = (const float*)d_in[7];
    const float* bias  = (const float*)d_in[8];
    float* out = (float*)d_out;

    float* pooled = (float*)d_ws;                           // 3072 floats

    pool_kernel<<<B_DIM * C_DIM, 256, 0, stream>>>(x, pooled);
    fused_dwconv_kernel<<<B_DIM * C_DIM / 2, 256, 0, stream>>>(
        x, pooled, w1, gamma, beta, rmean, rvar, w2, b2, bias, out);
}